// Round 8
// baseline (446.459 us; speedup 1.0000x reference)
//
#include <hip/hip_runtime.h>
#include <math.h>
#include <stdint.h>

#define N_NODES 32768
#define E_DIM   512
#define H_HEADS 8
#define D_HEAD  64
#define NNZ_E   524288

typedef __attribute__((ext_vector_type(4))) float f32x4;
typedef __attribute__((ext_vector_type(8))) short bf16x8;  // 8 bf16 = 4 VGPRs
typedef __attribute__((ext_vector_type(8))) short s16x8;

__device__ __forceinline__ unsigned short f32_to_bf16_rne(float f) {
  union { float f; uint32_t u; } v; v.f = f;
  const uint32_t u = v.u;
  return (unsigned short)((u + 0x7FFFu + ((u >> 16) & 1u)) >> 16);
}
__device__ __forceinline__ float bf16_to_f32(unsigned short h) {
  union { uint32_t u; float f; } v; v.u = ((uint32_t)h) << 16;
  return v.f;
}

// async 16B global->LDS (wave-uniform LDS base + lane*16)
__device__ __forceinline__ void async16(const unsigned short* g, unsigned short* l) {
  __builtin_amdgcn_global_load_lds(
      (const __attribute__((address_space(1))) void*)g,
      (__attribute__((address_space(3))) void*)l, 16, 0, 0);
}

// softmax-state merge; NaN (both m == -inf) -> clamp -80 -> weights 0
__device__ __forceinline__ void merge_state(
    float& m, float& l, float& aw, float& a0, float& a1, float& a2,
    float mo, float lo, float wo, float b0, float b1, float b2) {
  const float nm = fmaxf(m, mo);
  const float s1 = __expf(fmaxf(m - nm, -80.f));
  const float s2 = __expf(fmaxf(mo - nm, -80.f));
  m = nm;
  l = l * s1 + lo * s2;
  aw = aw * s1 + wo * s2;
  a0 = a0 * s1 + b0 * s2;
  a1 = a1 * s1 + b1 * s2;
  a2 = a2 * s1 + b2 * s2;
}

// ---------------------------------------------------------------------------
// Split fp32 matrix [rows][512] into bf16 hi|lo packed as [rows][1024].
// ---------------------------------------------------------------------------
__global__ __launch_bounds__(256) void cvt_split(
    const float* __restrict__ src, unsigned short* __restrict__ dst) {
  const int t = blockIdx.x * 256 + threadIdx.x;
  const int r = t >> 7;            // 128 float4 per row
  const int c4 = (t & 127) << 2;
  const float4 v = *(const float4*)(src + (size_t)r * 512 + c4);
  ushort4 hi, lo;
  hi.x = f32_to_bf16_rne(v.x); lo.x = f32_to_bf16_rne(v.x - bf16_to_f32(hi.x));
  hi.y = f32_to_bf16_rne(v.y); lo.y = f32_to_bf16_rne(v.y - bf16_to_f32(hi.y));
  hi.z = f32_to_bf16_rne(v.z); lo.z = f32_to_bf16_rne(v.z - bf16_to_f32(hi.z));
  hi.w = f32_to_bf16_rne(v.w); lo.w = f32_to_bf16_rne(v.w - bf16_to_f32(hi.w));
  *(ushort4*)(dst + (size_t)r * 1024 + c4) = hi;
  *(ushort4*)(dst + (size_t)r * 1024 + 512 + c4) = lo;
}

// ---------------------------------------------------------------------------
// Split-bf16 MFMA GEMM, merged-term K-loop (hi@hi + lo@hi + hi@lo, 48 MFMA
// per barrier pair). blockIdx.z: 0 -> q (fp32, *1/8), 1 -> k (int16, *4096).
// LDS XOR swizzle: chunk j of row r at j ^ ((r>>1)&3) -> conflict-free b128.
// ---------------------------------------------------------------------------
__global__ __launch_bounds__(256) void gemm_mfma(
    const unsigned short* __restrict__ xs,   // [N][1024] hi|lo
    const unsigned short* __restrict__ wqs,  // [512][1024] hi|lo
    const unsigned short* __restrict__ wks,
    const float* __restrict__ q_b, const float* __restrict__ k_b,
    float* __restrict__ qout, short* __restrict__ k16) {
  __shared__ unsigned short Ah[128 * 32];
  __shared__ unsigned short Al[128 * 32];
  __shared__ unsigned short Bh[128 * 32];
  __shared__ unsigned short Bl[128 * 32];
  const int tid = threadIdx.x;
  const int w = tid >> 6;        // wave 0..3
  const int l = tid & 63;
  const bool is_q = (blockIdx.z == 0);
  const unsigned short* __restrict__ wmat = is_q ? wqs : wks;
  const float* __restrict__ bias = is_q ? q_b : k_b;

  const int bm = blockIdx.x * 128;
  const int bn = blockIdx.y * 128;
  const int wm = (w & 1) * 64;   // wave's m-quadrant
  const int wn = (w >> 1) * 64;  // wave's n-quadrant

  f32x4 acc[4][4];
#pragma unroll
  for (int i = 0; i < 4; ++i)
#pragma unroll
    for (int j = 0; j < 4; ++j) acc[i][j] = (f32x4){0.f, 0.f, 0.f, 0.f};

  const int sr0 = w * 16 + (l >> 2);
  const int sr1 = sr0 + 64;
  const int sc = (((l & 3) ^ ((l >> 3) & 3)) << 3);
  const int fr = l & 15;
  const int fcs = ((((l >> 4) ^ ((fr >> 1) & 3)) & 3) << 3);

  const unsigned short* __restrict__ xa = xs + (size_t)bm * 1024;
  const unsigned short* __restrict__ wa = wmat + (size_t)bn * 1024;

  for (int k0 = 0; k0 < 512; k0 += 32) {
    async16(xa + (size_t)sr0 * 1024 + k0 + sc, Ah + w * 512);
    async16(xa + (size_t)sr1 * 1024 + k0 + sc, Ah + (w + 4) * 512);
    async16(xa + (size_t)sr0 * 1024 + 512 + k0 + sc, Al + w * 512);
    async16(xa + (size_t)sr1 * 1024 + 512 + k0 + sc, Al + (w + 4) * 512);
    async16(wa + (size_t)sr0 * 1024 + k0 + sc, Bh + w * 512);
    async16(wa + (size_t)sr1 * 1024 + k0 + sc, Bh + (w + 4) * 512);
    async16(wa + (size_t)sr0 * 1024 + 512 + k0 + sc, Bl + w * 512);
    async16(wa + (size_t)sr1 * 1024 + 512 + k0 + sc, Bl + (w + 4) * 512);
    __syncthreads();

    bf16x8 ah[4], bh[4], xl[4];
#pragma unroll
    for (int i = 0; i < 4; ++i) {
      ah[i] = *(const bf16x8*)(Ah + (wm + i * 16 + fr) * 32 + fcs);
      bh[i] = *(const bf16x8*)(Bh + (wn + i * 16 + fr) * 32 + fcs);
    }
#pragma unroll
    for (int i = 0; i < 4; ++i)
#pragma unroll
      for (int j = 0; j < 4; ++j)
        acc[i][j] = __builtin_amdgcn_mfma_f32_16x16x32_bf16(
            ah[i], bh[j], acc[i][j], 0, 0, 0);
#pragma unroll
    for (int i = 0; i < 4; ++i)
      xl[i] = *(const bf16x8*)(Al + (wm + i * 16 + fr) * 32 + fcs);
#pragma unroll
    for (int i = 0; i < 4; ++i)
#pragma unroll
      for (int j = 0; j < 4; ++j)
        acc[i][j] = __builtin_amdgcn_mfma_f32_16x16x32_bf16(
            xl[i], bh[j], acc[i][j], 0, 0, 0);
#pragma unroll
    for (int j = 0; j < 4; ++j)
      bh[j] = *(const bf16x8*)(Bl + (wn + j * 16 + fr) * 32 + fcs);
#pragma unroll
    for (int i = 0; i < 4; ++i)
#pragma unroll
      for (int j = 0; j < 4; ++j)
        acc[i][j] = __builtin_amdgcn_mfma_f32_16x16x32_bf16(
            ah[i], bh[j], acc[i][j], 0, 0, 0);
    __syncthreads();
  }

  const int cn = l & 15;
  const int cm4 = (l >> 4) * 4;
  float bvals[4];
#pragma unroll
  for (int j = 0; j < 4; ++j) bvals[j] = bias[bn + wn + j * 16 + cn];
#pragma unroll
  for (int i = 0; i < 4; ++i) {
#pragma unroll
    for (int r = 0; r < 4; ++r) {
      const int m = bm + wm + i * 16 + cm4 + r;
      if (is_q) {
        float* op = qout + (size_t)m * 512 + bn + wn + cn;
#pragma unroll
        for (int j = 0; j < 4; ++j)
          op[j * 16] = (acc[i][j][r] + bvals[j]) * 0.125f;
      } else {
        short* op = k16 + (size_t)m * 512 + bn + wn + cn;
#pragma unroll
        for (int j = 0; j < 4; ++j) {
          float v = (acc[i][j][r] + bvals[j]) * 4096.f;
          v = fmaxf(fminf(v, 32767.f), -32767.f);
          op[j * 16] = (short)__float2int_rn(v);
        }
      }
    }
  }
}

// ---------------------------------------------------------------------------
// Fused aux: ge[e] = to_col[col_index[e]]  +  CSR row_start from sorted rows.
// ---------------------------------------------------------------------------
__global__ void build_aux(const int* __restrict__ row_index,
                          const int* __restrict__ col_index,
                          const int* __restrict__ to_col,
                          int* __restrict__ row_start,
                          int* __restrict__ ge) {
  const int e = blockIdx.x * blockDim.x + threadIdx.x;
  if (e >= NNZ_E) return;
  ge[e] = to_col[col_index[e]];
  const int r0 = row_index[e];
  const int r1 = (e + 1 < NNZ_E) ? row_index[e + 1] : N_NODES;
  if (e == 0)
    for (int r = 0; r <= r0; ++r) row_start[r] = 0;
  for (int r = r0 + 1; r <= r1; ++r) row_start[r] = e + 1;
}

// ---------------------------------------------------------------------------
// Fused edge stage: one block (4 waves) per query row. Wave wv handles edges
// start + wv*4 + [0,4) stepping 16 (4-deep batched k-gather MLP). Per edge
// the wave computes all 8 head logits (8 fma + 3-shfl groups of 8), then
// updates one of 4 INDEPENDENT per-slot online-softmax states. Merge: 3
// in-register slot merges -> LDS (4 waves x 8 heads) -> 8 threads finalize.
// Eliminates the 32 MB logits round-trip and the row_featurize dispatch.
// ---------------------------------------------------------------------------
__global__ __launch_bounds__(256) void edge_fused(
    const float* __restrict__ q, const short* __restrict__ k16,
    const int* __restrict__ row_start, const int* __restrict__ col_index,
    const int* __restrict__ ge, const float* __restrict__ att_bias,
    const float* __restrict__ dist, const float* __restrict__ pos,
    const float* __restrict__ col_pos, float* __restrict__ out) {
  __shared__ float st[4][8][8];  // [wave][head][6 used]
  const int r = blockIdx.x;
  const int wv = threadIdx.x >> 6;
  const int lane = threadIdx.x & 63;
  const int h = lane >> 3;
  const int start = row_start[r];
  const int end = row_start[r + 1];

  // q row loaded once per block: lane holds floats [8*lane, 8*lane+8)
  const int lo = lane * 8;
  const float* qp = q + (size_t)r * E_DIM + lo;
  const float4 q0 = *(const float4*)(qp + 0);
  const float4 q1 = *(const float4*)(qp + 4);

  float m[4], l[4], aw[4], a0[4], a1[4], a2[4];
#pragma unroll
  for (int i = 0; i < 4; ++i) {
    m[i] = -INFINITY; l[i] = 0.f; aw[i] = 0.f;
    a0[i] = 0.f; a1[i] = 0.f; a2[i] = 0.f;
  }

  for (int base = start + wv * 4; base < end; base += 16) {
    const int cnt = end - base;  // active slots = min(4, cnt)
    s16x8 kv[4];
    float bs[4], dw[4], c0[4], c1[4], c2[4];
    // issue all k-gathers first (the long-latency loads)
#pragma unroll
    for (int i = 0; i < 4; ++i) {
      if (i < cnt) {
        const int g = ge[base + i];
        kv[i] = *(const s16x8*)(k16 + (size_t)g * E_DIM + lo);
      }
    }
#pragma unroll
    for (int i = 0; i < 4; ++i) {
      if (i < cnt) {
        bs[i] = att_bias[(size_t)h * NNZ_E + base + i];
        const float dd = dist[base + i];
        dw[i] = (dd == 0.f) ? 0.f : 1.f / dd;
        const int c = col_index[base + i];
        c0[i] = col_pos[c * 3 + 0];
        c1[i] = col_pos[c * 3 + 1];
        c2[i] = col_pos[c * 3 + 2];
      }
    }
#pragma unroll
    for (int i = 0; i < 4; ++i) {
      if (i < cnt) {
        float s = q0.x * (float)kv[i][0];
        s = fmaf(q0.y, (float)kv[i][1], s);
        s = fmaf(q0.z, (float)kv[i][2], s);
        s = fmaf(q0.w, (float)kv[i][3], s);
        s = fmaf(q1.x, (float)kv[i][4], s);
        s = fmaf(q1.y, (float)kv[i][5], s);
        s = fmaf(q1.z, (float)kv[i][6], s);
        s = fmaf(q1.w, (float)kv[i][7], s);
        s += __shfl_xor(s, 1);
        s += __shfl_xor(s, 2);
        s += __shfl_xor(s, 4);
        s = s * (1.f / 4096.f) + bs[i];
        const float nm = fmaxf(m[i], s);
        const float sc = __expf(m[i] - nm);  // first iter: exp(-inf)=0
        const float p = __expf(s - nm);
        m[i] = nm;
        l[i] = fmaf(l[i], sc, p);
        const float pw = p * dw[i];
        aw[i] = fmaf(aw[i], sc, pw);
        a0[i] = fmaf(a0[i], sc, pw * c0[i]);
        a1[i] = fmaf(a1[i], sc, pw * c1[i]);
        a2[i] = fmaf(a2[i], sc, pw * c2[i]);
      }
    }
  }

  // merge the 4 slots (all 8 lanes of a group hold identical state)
  merge_state(m[0], l[0], aw[0], a0[0], a1[0], a2[0],
              m[1], l[1], aw[1], a0[1], a1[1], a2[1]);
  merge_state(m[2], l[2], aw[2], a0[2], a1[2], a2[2],
              m[3], l[3], aw[3], a0[3], a1[3], a2[3]);
  merge_state(m[0], l[0], aw[0], a0[0], a1[0], a2[0],
              m[2], l[2], aw[2], a0[2], a1[2], a2[2]);

  if ((lane & 7) == 0) {
    st[wv][h][0] = m[0]; st[wv][h][1] = l[0]; st[wv][h][2] = aw[0];
    st[wv][h][3] = a0[0]; st[wv][h][4] = a1[0]; st[wv][h][5] = a2[0];
  }
  __syncthreads();

  if (threadIdx.x < 8) {
    const int hh = threadIdx.x;
    float M = st[0][hh][0], L = st[0][hh][1], AW = st[0][hh][2];
    float A0 = st[0][hh][3], A1 = st[0][hh][4], A2 = st[0][hh][5];
#pragma unroll
    for (int w2 = 1; w2 < 4; ++w2)
      merge_state(M, L, AW, A0, A1, A2,
                  st[w2][hh][0], st[w2][hh][1], st[w2][hh][2],
                  st[w2][hh][3], st[w2][hh][4], st[w2][hh][5]);
    const float invz = (L > 0.f) ? 1.f / L : 0.f;
    const float avg = AW * invz;
    const float v0 = A0 * invz - avg * pos[r * 3 + 0];
    const float v1 = A1 * invz - avg * pos[r * 3 + 1];
    const float v2 = A2 * invz - avg * pos[r * 3 + 2];
    const float nrm = sqrtf(v0 * v0 + v1 * v1 + v2 * v2);
    const float invn = 1.f / fmaxf(nrm, 1e-12f);
    float4 o;
    o.x = v0 * invn; o.y = v1 * invn; o.z = v2 * invn; o.w = avg;
    *(float4*)(out + (size_t)r * (H_HEADS * 4) + hh * 4) = o;
  }
}

// ---------------------------------------------------------------------------
extern "C" void kernel_launch(void* const* d_in, const int* in_sizes, int n_in,
                              void* d_out, int out_size, void* d_ws,
                              size_t ws_size, hipStream_t stream) {
  const float* x        = (const float*)d_in[0];
  const int* row_index  = (const int*)d_in[1];
  const int* col_index  = (const int*)d_in[2];
  const int* to_col     = (const int*)d_in[3];
  const float* att_bias = (const float*)d_in[4];
  const float* dist     = (const float*)d_in[5];
  const float* pos      = (const float*)d_in[6];
  const float* col_pos  = (const float*)d_in[7];
  const float* q_w      = (const float*)d_in[8];
  const float* q_b      = (const float*)d_in[9];
  const float* k_w      = (const float*)d_in[10];
  const float* k_b      = (const float*)d_in[11];
  float* out = (float*)d_out;

  // ws: q[N*E f32] | k16[N*E s16] | xsplit[N*1024 bf16] | wq_s | wk_s
  //     | row_start[N+1] | ge[NNZ]
  float* q = (float*)d_ws;
  short* k16 = (short*)(q + (size_t)N_NODES * E_DIM);
  unsigned short* xsplit = (unsigned short*)(k16 + (size_t)N_NODES * E_DIM);
  unsigned short* wq_s = xsplit + (size_t)N_NODES * 1024;
  unsigned short* wk_s = wq_s + 512 * 1024;
  int* row_start = (int*)(wk_s + 512 * 1024);
  int* ge = row_start + (N_NODES + 1);

  build_aux<<<NNZ_E / 256, 256, 0, stream>>>(row_index, col_index, to_col,
                                             row_start, ge);
  cvt_split<<<N_NODES / 2, 256, 0, stream>>>(x, xsplit);
  cvt_split<<<256, 256, 0, stream>>>(q_w, wq_s);
  cvt_split<<<256, 256, 0, stream>>>(k_w, wk_s);

  dim3 gg(N_NODES / 128, E_DIM / 128, 2);
  gemm_mfma<<<gg, 256, 0, stream>>>(xsplit, wq_s, wk_s, q_b, k_b, q, k16);

  edge_fused<<<N_NODES, 256, 0, stream>>>(q, k16, row_start, col_index, ge,
                                          att_bias, dist, pos, col_pos, out);
}

// Round 9
// 371.568 us; speedup vs baseline: 1.2016x; 1.2016x over previous
//
#include <hip/hip_runtime.h>
#include <math.h>
#include <stdint.h>

#define N_NODES 32768
#define E_DIM   512
#define H_HEADS 8
#define D_HEAD  64
#define NNZ_E   524288

typedef __attribute__((ext_vector_type(4))) float f32x4;
typedef __attribute__((ext_vector_type(8))) short bf16x8;  // 8 bf16 = 4 VGPRs
typedef __attribute__((ext_vector_type(8))) short s16x8;

__device__ __forceinline__ unsigned short f32_to_bf16_rne(float f) {
  union { float f; uint32_t u; } v; v.f = f;
  const uint32_t u = v.u;
  return (unsigned short)((u + 0x7FFFu + ((u >> 16) & 1u)) >> 16);
}
__device__ __forceinline__ float bf16_to_f32(unsigned short h) {
  union { uint32_t u; float f; } v; v.u = ((uint32_t)h) << 16;
  return v.f;
}

// async 16B global->LDS (wave-uniform LDS base + lane*16)
__device__ __forceinline__ void async16(const unsigned short* g, unsigned short* l) {
  __builtin_amdgcn_global_load_lds(
      (const __attribute__((address_space(1))) void*)g,
      (__attribute__((address_space(3))) void*)l, 16, 0, 0);
}

// ---------------------------------------------------------------------------
// Split fp32 matrix [rows][512] into bf16 hi|lo packed as [rows][1024].
// ---------------------------------------------------------------------------
__global__ __launch_bounds__(256) void cvt_split(
    const float* __restrict__ src, unsigned short* __restrict__ dst) {
  const int t = blockIdx.x * 256 + threadIdx.x;
  const int r = t >> 7;            // 128 float4 per row
  const int c4 = (t & 127) << 2;
  const float4 v = *(const float4*)(src + (size_t)r * 512 + c4);
  ushort4 hi, lo;
  hi.x = f32_to_bf16_rne(v.x); lo.x = f32_to_bf16_rne(v.x - bf16_to_f32(hi.x));
  hi.y = f32_to_bf16_rne(v.y); lo.y = f32_to_bf16_rne(v.y - bf16_to_f32(hi.y));
  hi.z = f32_to_bf16_rne(v.z); lo.z = f32_to_bf16_rne(v.z - bf16_to_f32(hi.z));
  hi.w = f32_to_bf16_rne(v.w); lo.w = f32_to_bf16_rne(v.w - bf16_to_f32(hi.w));
  *(ushort4*)(dst + (size_t)r * 1024 + c4) = hi;
  *(ushort4*)(dst + (size_t)r * 1024 + 512 + c4) = lo;
}

// ---------------------------------------------------------------------------
// Split-bf16 MFMA GEMM, merged-term K-loop (hi@hi + lo@hi + hi@lo, 48 MFMA
// per barrier pair). blockIdx.z: 0 -> q (fp32, *1/8), 1 -> k (int16, *4096).
// LDS XOR swizzle: chunk j of row r at j ^ ((r>>1)&3) -> conflict-free b128.
// ---------------------------------------------------------------------------
__global__ __launch_bounds__(256) void gemm_mfma(
    const unsigned short* __restrict__ xs,   // [N][1024] hi|lo
    const unsigned short* __restrict__ wqs,  // [512][1024] hi|lo
    const unsigned short* __restrict__ wks,
    const float* __restrict__ q_b, const float* __restrict__ k_b,
    float* __restrict__ qout, short* __restrict__ k16) {
  __shared__ unsigned short Ah[128 * 32];
  __shared__ unsigned short Al[128 * 32];
  __shared__ unsigned short Bh[128 * 32];
  __shared__ unsigned short Bl[128 * 32];
  const int tid = threadIdx.x;
  const int w = tid >> 6;        // wave 0..3
  const int l = tid & 63;
  const bool is_q = (blockIdx.z == 0);
  const unsigned short* __restrict__ wmat = is_q ? wqs : wks;
  const float* __restrict__ bias = is_q ? q_b : k_b;

  const int bm = blockIdx.x * 128;
  const int bn = blockIdx.y * 128;
  const int wm = (w & 1) * 64;   // wave's m-quadrant
  const int wn = (w >> 1) * 64;  // wave's n-quadrant

  f32x4 acc[4][4];
#pragma unroll
  for (int i = 0; i < 4; ++i)
#pragma unroll
    for (int j = 0; j < 4; ++j) acc[i][j] = (f32x4){0.f, 0.f, 0.f, 0.f};

  const int sr0 = w * 16 + (l >> 2);
  const int sr1 = sr0 + 64;
  const int sc = (((l & 3) ^ ((l >> 3) & 3)) << 3);
  const int fr = l & 15;
  const int fcs = ((((l >> 4) ^ ((fr >> 1) & 3)) & 3) << 3);

  const unsigned short* __restrict__ xa = xs + (size_t)bm * 1024;
  const unsigned short* __restrict__ wa = wmat + (size_t)bn * 1024;

  for (int k0 = 0; k0 < 512; k0 += 32) {
    async16(xa + (size_t)sr0 * 1024 + k0 + sc, Ah + w * 512);
    async16(xa + (size_t)sr1 * 1024 + k0 + sc, Ah + (w + 4) * 512);
    async16(xa + (size_t)sr0 * 1024 + 512 + k0 + sc, Al + w * 512);
    async16(xa + (size_t)sr1 * 1024 + 512 + k0 + sc, Al + (w + 4) * 512);
    async16(wa + (size_t)sr0 * 1024 + k0 + sc, Bh + w * 512);
    async16(wa + (size_t)sr1 * 1024 + k0 + sc, Bh + (w + 4) * 512);
    async16(wa + (size_t)sr0 * 1024 + 512 + k0 + sc, Bl + w * 512);
    async16(wa + (size_t)sr1 * 1024 + 512 + k0 + sc, Bl + (w + 4) * 512);
    __syncthreads();

    bf16x8 ah[4], bh[4], xl[4];
#pragma unroll
    for (int i = 0; i < 4; ++i) {
      ah[i] = *(const bf16x8*)(Ah + (wm + i * 16 + fr) * 32 + fcs);
      bh[i] = *(const bf16x8*)(Bh + (wn + i * 16 + fr) * 32 + fcs);
    }
#pragma unroll
    for (int i = 0; i < 4; ++i)
#pragma unroll
      for (int j = 0; j < 4; ++j)
        acc[i][j] = __builtin_amdgcn_mfma_f32_16x16x32_bf16(
            ah[i], bh[j], acc[i][j], 0, 0, 0);
#pragma unroll
    for (int i = 0; i < 4; ++i)
      xl[i] = *(const bf16x8*)(Al + (wm + i * 16 + fr) * 32 + fcs);
#pragma unroll
    for (int i = 0; i < 4; ++i)
#pragma unroll
      for (int j = 0; j < 4; ++j)
        acc[i][j] = __builtin_amdgcn_mfma_f32_16x16x32_bf16(
            xl[i], bh[j], acc[i][j], 0, 0, 0);
#pragma unroll
    for (int j = 0; j < 4; ++j)
      bh[j] = *(const bf16x8*)(Bl + (wn + j * 16 + fr) * 32 + fcs);
#pragma unroll
    for (int i = 0; i < 4; ++i)
#pragma unroll
      for (int j = 0; j < 4; ++j)
        acc[i][j] = __builtin_amdgcn_mfma_f32_16x16x32_bf16(
            ah[i], bh[j], acc[i][j], 0, 0, 0);
    __syncthreads();
  }

  const int cn = l & 15;
  const int cm4 = (l >> 4) * 4;
  float bvals[4];
#pragma unroll
  for (int j = 0; j < 4; ++j) bvals[j] = bias[bn + wn + j * 16 + cn];
#pragma unroll
  for (int i = 0; i < 4; ++i) {
#pragma unroll
    for (int r = 0; r < 4; ++r) {
      const int m = bm + wm + i * 16 + cm4 + r;
      if (is_q) {
        float* op = qout + (size_t)m * 512 + bn + wn + cn;
#pragma unroll
        for (int j = 0; j < 4; ++j)
          op[j * 16] = (acc[i][j][r] + bvals[j]) * 0.125f;
      } else {
        short* op = k16 + (size_t)m * 512 + bn + wn + cn;
#pragma unroll
        for (int j = 0; j < 4; ++j) {
          float v = (acc[i][j][r] + bvals[j]) * 4096.f;
          v = fmaxf(fminf(v, 32767.f), -32767.f);
          op[j * 16] = (short)__float2int_rn(v);
        }
      }
    }
  }
}

// ---------------------------------------------------------------------------
// Fused aux: ge[e] = to_col[col_index[e]]  +  CSR row_start from sorted rows.
// ---------------------------------------------------------------------------
__global__ void build_aux(const int* __restrict__ row_index,
                          const int* __restrict__ col_index,
                          const int* __restrict__ to_col,
                          int* __restrict__ row_start,
                          int* __restrict__ ge) {
  const int e = blockIdx.x * blockDim.x + threadIdx.x;
  if (e >= NNZ_E) return;
  ge[e] = to_col[col_index[e]];
  const int r0 = row_index[e];
  const int r1 = (e + 1 < NNZ_E) ? row_index[e + 1] : N_NODES;
  if (e == 0)
    for (int r = 0; r <= r0; ++r) row_start[r] = 0;
  for (int r = r0 + 1; r <= r1; ++r) row_start[r] = e + 1;
}

// ---------------------------------------------------------------------------
// Phase A: 8 edges per wave, all 8 k-gathers (16B int16 rows) + q loads
// issued before any compute -> 8 KB k-data in flight per wave (restores the
// r4 in-flight depth that measured 3.76 TB/s, at half the bytes; the r6/r7
// 4-edge version had only 4 KB in flight and was MLP-limited to ~1.8 TB/s).
// ---------------------------------------------------------------------------
__global__ __launch_bounds__(256) void edge_logits(
    const float* __restrict__ q, const short* __restrict__ k16,
    const int* __restrict__ row_index, const int* __restrict__ ge,
    const float* __restrict__ att_bias, float* __restrict__ logits) {
  const int wave = threadIdx.x >> 6;
  const int lane = threadIdx.x & 63;
  const int e0 = __builtin_amdgcn_readfirstlane((blockIdx.x * 4 + wave) * 8);

  int r[8], g[8];
#pragma unroll
  for (int i = 0; i < 8; ++i) {
    r[i] = row_index[e0 + i];
    g[i] = ge[e0 + i];
  }

  const int lo = lane * 8;
  s16x8 kv[8];
#pragma unroll
  for (int i = 0; i < 8; ++i)
    kv[i] = *(const s16x8*)(k16 + (size_t)g[i] * E_DIM + lo);

  float4 qv[8][2];
#pragma unroll
  for (int i = 0; i < 8; ++i) {
    const float* qp = q + (size_t)r[i] * E_DIM + lo;
    qv[i][0] = *(const float4*)(qp + 0);
    qv[i][1] = *(const float4*)(qp + 4);
  }

  const int h = lane >> 3;
#pragma unroll
  for (int i = 0; i < 8; ++i) {
    float s = qv[i][0].x * (float)kv[i][0];
    s = fmaf(qv[i][0].y, (float)kv[i][1], s);
    s = fmaf(qv[i][0].z, (float)kv[i][2], s);
    s = fmaf(qv[i][0].w, (float)kv[i][3], s);
    s = fmaf(qv[i][1].x, (float)kv[i][4], s);
    s = fmaf(qv[i][1].y, (float)kv[i][5], s);
    s = fmaf(qv[i][1].z, (float)kv[i][6], s);
    s = fmaf(qv[i][1].w, (float)kv[i][7], s);
    s += __shfl_xor(s, 1);
    s += __shfl_xor(s, 2);
    s += __shfl_xor(s, 4);
    if ((lane & 7) == 0) {
      logits[(size_t)(e0 + i) * H_HEADS + h] =
          s * (1.f / 4096.f) + att_bias[(size_t)h * NNZ_E + e0 + i];
    }
  }
}

// ---------------------------------------------------------------------------
// Phase B: 4 rows per block (1 wave per row); lane (h,j) strided
// online-softmax + 3-step merge.
// ---------------------------------------------------------------------------
__global__ __launch_bounds__(256) void row_featurize(
    const float* __restrict__ logits, const int* __restrict__ row_start,
    const int* __restrict__ col_index, const float* __restrict__ dist,
    const float* __restrict__ pos, const float* __restrict__ col_pos,
    float* __restrict__ out) {
  const int r = blockIdx.x * 4 + (threadIdx.x >> 6);
  const int lane = threadIdx.x & 63;
  const int h = lane >> 3;
  const int j = lane & 7;
  const int start = row_start[r];
  const int end = row_start[r + 1];

  float m = -INFINITY, l = 0.f, accw = 0.f, a0 = 0.f, a1 = 0.f, a2 = 0.f;

  for (int e = start + j; e < end; e += 8) {
    const float s = logits[(size_t)e * H_HEADS + h];
    const float dd = dist[e];
    const float w = (dd == 0.f) ? 0.f : 1.f / dd;
    const int c = col_index[e];
    const float nm = fmaxf(m, s);
    const float sc = __expf(m - nm);
    const float p = __expf(s - nm);
    m = nm;
    l = fmaf(l, sc, p);
    const float pw = p * w;
    accw = fmaf(accw, sc, pw);
    a0 = fmaf(a0, sc, pw * col_pos[c * 3 + 0]);
    a1 = fmaf(a1, sc, pw * col_pos[c * 3 + 1]);
    a2 = fmaf(a2, sc, pw * col_pos[c * 3 + 2]);
  }

#pragma unroll
  for (int off = 1; off < 8; off <<= 1) {
    const float mo = __shfl_xor(m, off);
    const float lo = __shfl_xor(l, off);
    const float wo = __shfl_xor(accw, off);
    const float b0 = __shfl_xor(a0, off);
    const float b1 = __shfl_xor(a1, off);
    const float b2 = __shfl_xor(a2, off);
    const float nm = fmaxf(m, mo);
    const float s1 = __expf(fmaxf(m - nm, -80.f));  // NaN (inf-inf) -> -80
    const float s2 = __expf(fmaxf(mo - nm, -80.f));
    m = nm;
    l = l * s1 + lo * s2;
    accw = accw * s1 + wo * s2;
    a0 = a0 * s1 + b0 * s2;
    a1 = a1 * s1 + b1 * s2;
    a2 = a2 * s1 + b2 * s2;
  }

  if (j == 0) {
    const float invz = (l > 0.f) ? 1.f / l : 0.f;
    const float avg = accw * invz;
    const float v0 = a0 * invz - avg * pos[r * 3 + 0];
    const float v1 = a1 * invz - avg * pos[r * 3 + 1];
    const float v2 = a2 * invz - avg * pos[r * 3 + 2];
    const float nrm = sqrtf(v0 * v0 + v1 * v1 + v2 * v2);
    const float invn = 1.f / fmaxf(nrm, 1e-12f);
    float4 o;
    o.x = v0 * invn; o.y = v1 * invn; o.z = v2 * invn; o.w = avg;
    *(float4*)(out + (size_t)r * (H_HEADS * 4) + h * 4) = o;
  }
}

// ---------------------------------------------------------------------------
extern "C" void kernel_launch(void* const* d_in, const int* in_sizes, int n_in,
                              void* d_out, int out_size, void* d_ws,
                              size_t ws_size, hipStream_t stream) {
  const float* x        = (const float*)d_in[0];
  const int* row_index  = (const int*)d_in[1];
  const int* col_index  = (const int*)d_in[2];
  const int* to_col     = (const int*)d_in[3];
  const float* att_bias = (const float*)d_in[4];
  const float* dist     = (const float*)d_in[5];
  const float* pos      = (const float*)d_in[6];
  const float* col_pos  = (const float*)d_in[7];
  const float* q_w      = (const float*)d_in[8];
  const float* q_b      = (const float*)d_in[9];
  const float* k_w      = (const float*)d_in[10];
  const float* k_b      = (const float*)d_in[11];
  float* out = (float*)d_out;

  // ws: q[N*E f32] | k16[N*E s16] | xsplit[N*1024 bf16] (aliased by logits)
  //     | wq_s | wk_s | row_start[N+1] | ge[NNZ]
  float* q = (float*)d_ws;
  short* k16 = (short*)(q + (size_t)N_NODES * E_DIM);
  unsigned short* xsplit = (unsigned short*)(k16 + (size_t)N_NODES * E_DIM);
  float* logits = (float*)xsplit;  // xsplit dead after gemm_mfma
  unsigned short* wq_s = xsplit + (size_t)N_NODES * 1024;
  unsigned short* wk_s = wq_s + 512 * 1024;
  int* row_start = (int*)(wk_s + 512 * 1024);
  int* ge = row_start + (N_NODES + 1);

  cvt_split<<<N_NODES / 2, 256, 0, stream>>>(x, xsplit);
  cvt_split<<<256, 256, 0, stream>>>(q_w, wq_s);
  cvt_split<<<256, 256, 0, stream>>>(k_w, wk_s);

  dim3 gg(N_NODES / 128, E_DIM / 128, 2);
  gemm_mfma<<<gg, 256, 0, stream>>>(xsplit, wq_s, wk_s, q_b, k_b, q, k16);

  build_aux<<<NNZ_E / 256, 256, 0, stream>>>(row_index, col_index, to_col,
                                             row_start, ge);
  edge_logits<<<NNZ_E / 32, 256, 0, stream>>>(q, k16, row_index, ge,
                                              att_bias, logits);
  row_featurize<<<N_NODES / 4, 256, 0, stream>>>(logits, row_start, col_index,
                                                 dist, pos, col_pos, out);
}